// Round 14
// baseline (1378.699 us; speedup 1.0000x reference)
//
#include <hip/hip_runtime.h>
#include <hip/hip_cooperative_groups.h>

namespace cg = cooperative_groups;

#define NN 50000
#define NE 800000
#define KH 4
#define FIN 6
#define FH 128
#define FO 6
#define ADIM 3
#define NN8 (NN * 8)
#define NBKT 196
#define EPB 2048
#define NPB 391
#define CAP 6144
#define ROWMASK 0xFFFFFu
#define NEPAD (NE + NBKT * 1024)
#define NCH 4
#define NDB 196
#define GRID_G 768      // 3 blocks/CU on 256 CUs (cooperative co-residency)

typedef unsigned int u32;
typedef _Float16 f16;
typedef f16 f16x8 __attribute__((ext_vector_type(8)));

struct __align__(8) Edge { u32 r; float w; };

__device__ __forceinline__ float h2f_bits(u32 hb) {
    union { unsigned short us; f16 h; } c; c.us = (unsigned short)hb; return (float)c.h;
}
__device__ __forceinline__ u32 f2h_bits(float f) {
    union { unsigned short us; f16 h; } c; c.h = (f16)f; return (u32)c.us;
}
__device__ __forceinline__ u32 pack2(float a, float b) {
    return f2h_bits(a) | (f2h_bits(b) << 16);
}

struct Params {
    const float* x; const int* row; const int* col; const float* ew;
    const float* W1; const float* b1; const float* W2; const float* b2;
    float* out;
    f16* xpad; f16* xs; f16* y4h; f16* za; f16* zb;
    float* ys; float* pacc; float* W1T; float* W2T;
    Edge* etmp; u32* edges; u32* ghist; u32* bbase; u32* bcur;
    int* offs; int* eoff; float* dinv;
};

// ================= phase bodies (shared by mega kernel + fallback kernels) =================

__device__ void padx_body(int gtid, int gsz, const float* __restrict__ x, f16* __restrict__ xpad,
                          const float* __restrict__ W1, const float* __restrict__ W2,
                          float* __restrict__ W1T, float* __restrict__ W2T) {
    for (int i = gtid; i < 30 * FH; i += gsz) {
        int f = i / 30, k6 = i - f * 30;
        W1T[i] = W1[k6 * FH + f];
        int k = k6 / 6, a = k6 - k * 6;
        W2T[i] = W2[((size_t)k * FH + f) * FO + a];
    }
    for (int i = gtid; i < NN8; i += gsz) {
        int n = i >> 3, c = i & 7;
        xpad[i] = (c < 6) ? (f16)x[n * 6 + c] : (f16)0.f;
    }
}

__device__ void hist_body(int blk, int t, const int* __restrict__ col,
                          u32* __restrict__ ghist, u32* sm) {
    u32* h = sm;   // NBKT
    for (int i = t; i < NBKT; i += 256) h[i] = 0;
    __syncthreads();
    int base = blk * EPB;
#pragma unroll
    for (int i = 0; i < EPB / 256; ++i) {
        int e = base + i * 256 + t;
        if (e < NE) atomicAdd(&h[((u32)col[e]) >> 8], 1u);
    }
    __syncthreads();
    for (int i = t; i < NBKT; i += 256)
        if (h[i]) atomicAdd(&ghist[i], h[i]);
}

__device__ void scan_body(int t, const u32* __restrict__ ghist, u32* __restrict__ bbase,
                          u32* __restrict__ bcur, u32* sm) {
    u32* sh = sm;  // 256
    u32 v = (t < NBKT) ? ghist[t] : 0;
    sh[t] = v;
    __syncthreads();
    for (int off = 1; off < 256; off <<= 1) {
        u32 u = (t >= off) ? sh[t - off] : 0;
        __syncthreads();
        sh[t] += u;
        __syncthreads();
    }
    if (t < NBKT) { bbase[t] = sh[t] - v; bcur[t] = sh[t] - v; }
    if (t == NBKT - 1) bbase[NBKT] = sh[t];
}

__device__ void partition_body(int blk, int t, const int* __restrict__ row,
                               const int* __restrict__ col, const float* __restrict__ w,
                               u32* __restrict__ bcur, Edge* __restrict__ etmp, u32* sm) {
    u32* hcnt = sm;                     // 196
    u32* hloc = sm + 196;               // 196
    u32* hglb = sm + 392;               // 196
    u32* sc   = sm + 588;               // 256
    u32* smeta = sm + 844;              // EPB
    float* swt = (float*)(sm + 844 + EPB);   // EPB
    u32* sgid = sm + 844 + 2 * EPB;     // EPB  (total 6988)
    for (int i = t; i < NBKT; i += 256) hcnt[i] = 0;
    __syncthreads();
    int base = blk * EPB;
    u32 m_[8]; float w_[8]; u32 b_[8]; u32 rk_[8]; int v_[8];
#pragma unroll
    for (int i = 0; i < 8; ++i) {
        int e = base + i * 256 + t;
        v_[i] = e < NE;
        if (v_[i]) {
            u32 c = (u32)col[e];
            u32 r = (u32)row[e];
            b_[i] = c >> 8;
            m_[i] = ((c & 255u) << 20) | r;
            w_[i] = w[e];
            rk_[i] = atomicAdd(&hcnt[b_[i]], 1u);
        }
    }
    __syncthreads();
    {
        u32 v = (t < NBKT) ? hcnt[t] : 0;
        sc[t] = v;
        __syncthreads();
        for (int off = 1; off < 256; off <<= 1) {
            u32 u = (t >= off) ? sc[t - off] : 0;
            __syncthreads();
            sc[t] += u;
            __syncthreads();
        }
        if (t < NBKT) hloc[t] = sc[t] - v;
    }
    __syncthreads();
    for (int i = t; i < NBKT; i += 256)
        if (hcnt[i]) hglb[i] = atomicAdd(&bcur[i], hcnt[i]);
    __syncthreads();
#pragma unroll
    for (int i = 0; i < 8; ++i) if (v_[i]) {
        u32 slot = hloc[b_[i]] + rk_[i];
        smeta[slot] = m_[i];
        swt[slot] = w_[i];
        sgid[slot] = hglb[b_[i]] + rk_[i];
    }
    __syncthreads();
    int tot = NE - base; if (tot > EPB) tot = EPB;
    for (int s = t; s < tot; s += 256) {
        Edge ed; ed.r = smeta[s]; ed.w = swt[s];
        etmp[sgid[s]] = ed;
    }
}

__device__ void csr_body(int b, int t, const u32* __restrict__ bbase,
                         const Edge* __restrict__ etmp, u32* __restrict__ edges,
                         int* __restrict__ offs, int* __restrict__ eoff,
                         float* __restrict__ dinv, u32* sm) {
    u32* ncnt = sm;                 // 256
    float* nsum = (float*)(sm + 256);
    u32* ncur = sm + 512;
    u32* sc = sm + 768;
    u32* stage = sm + 1024;         // CAP (total 7168)
    u32 s = bbase[b], e = bbase[b + 1];
    int cnt = (int)(e - s);
    u32 rb = s + (u32)b * 1024u;
    int node0 = b << 8;
    int nloc = NN - node0; if (nloc > 256) nloc = 256;
    ncnt[t] = 0; nsum[t] = 0.f;
    __syncthreads();
    for (int i = t; i < cnt; i += 256) {
        Edge ed = etmp[s + i];
        u32 cl = ed.r >> 20;
        atomicAdd(&ncnt[cl], 1u);
        atomicAdd(&nsum[cl], ed.w);
    }
    __syncthreads();
    u32 v = ncnt[t];
    u32 pv = (v + 3u) & ~3u;
    sc[t] = pv;
    __syncthreads();
    for (int off = 1; off < 256; off <<= 1) {
        u32 u = (t >= off) ? sc[t - off] : 0;
        __syncthreads();
        sc[t] += u;
        __syncthreads();
    }
    u32 excl = sc[t] - pv;
    u32 ptot = sc[255];
    ncur[t] = excl;
    if (t < nloc) {
        offs[node0 + t] = (int)(rb + excl);
        eoff[node0 + t] = (int)(rb + excl + pv);
        float d = nsum[t];
        dinv[node0 + t] = d > 0.f ? rsqrtf(d) : 0.f;
    }
    __syncthreads();
    for (int i = t; i < cnt; i += 256) {
        Edge ed = etmp[s + i];
        u32 cl = ed.r >> 20;
        u32 slot = atomicAdd(&ncur[cl], 1u);
        u32 pw = (ed.r & ROWMASK) | (f2h_bits(ed.w) << 16);
        if (slot < CAP) stage[slot] = pw;
        else edges[rb + slot] = pw;
    }
    if (t < nloc) {
        for (u32 slot = excl + v; slot < excl + pv; ++slot) {
            if (slot < CAP) stage[slot] = 0u;
            else edges[rb + slot] = 0u;
        }
    }
    __syncthreads();
    int lim = (int)(ptot < CAP ? ptot : CAP);
    for (int i = t; i < lim; i += 256) edges[rb + i] = stage[i];
}

__device__ __forceinline__ void gath(const f16* __restrict__ xp, u32 r, float w,
                                     float& a0, float& a1, float& a2,
                                     float& a3, float& a4, float& a5) {
    f16x8 v = *(const f16x8*)(xp + (size_t)r * 8);
    a0 += w * (float)v[0]; a1 += w * (float)v[1]; a2 += w * (float)v[2];
    a3 += w * (float)v[3]; a4 += w * (float)v[4]; a5 += w * (float)v[5];
}

__device__ __forceinline__ void hop_unit(int u, const int* __restrict__ offs,
        const int* __restrict__ eoff, const u32* __restrict__ edges,
        const f16* __restrict__ xprev, const float* __restrict__ yadd,
        f16* __restrict__ xnext) {
    int n = u >> 2, j = u & 3;
    int s = offs[n], e = eoff[n];
    float a0 = 0.f, a1 = 0.f, a2 = 0.f, a3 = 0.f, a4 = 0.f, a5 = 0.f;
    for (int i = s + 4 * j; i < e; i += 16) {
        int4 q = *(const int4*)(edges + i);
        { u32 wd = (u32)q.x; gath(xprev, wd & 0xFFFFu, h2f_bits(wd >> 16), a0, a1, a2, a3, a4, a5); }
        { u32 wd = (u32)q.y; gath(xprev, wd & 0xFFFFu, h2f_bits(wd >> 16), a0, a1, a2, a3, a4, a5); }
        { u32 wd = (u32)q.z; gath(xprev, wd & 0xFFFFu, h2f_bits(wd >> 16), a0, a1, a2, a3, a4, a5); }
        { u32 wd = (u32)q.w; gath(xprev, wd & 0xFFFFu, h2f_bits(wd >> 16), a0, a1, a2, a3, a4, a5); }
    }
#pragma unroll
    for (int d = 1; d < 4; d <<= 1) {
        a0 += __shfl_xor(a0, d); a1 += __shfl_xor(a1, d); a2 += __shfl_xor(a2, d);
        a3 += __shfl_xor(a3, d); a4 += __shfl_xor(a4, d); a5 += __shfl_xor(a5, d);
    }
    float v0 = j == 0 ? a0 : j == 1 ? a2 : j == 2 ? a4 : 0.f;
    float v1 = j == 0 ? a1 : j == 1 ? a3 : j == 2 ? a5 : 0.f;
    if (yadd && j < 3) {
        v0 += yadd[(size_t)n * 32 + 2 * j];
        v1 += yadd[(size_t)n * 32 + 2 * j + 1];
    }
    ((u32*)xnext)[(size_t)n * 4 + j] = pack2(v0, v1);
}

__device__ __forceinline__ void hopnorm_unit(int u, const int* __restrict__ offs,
        const int* __restrict__ eoff, u32* __restrict__ edges,
        const float* __restrict__ dinv, const f16* __restrict__ xpad,
        f16* __restrict__ xnext) {
    int n = u >> 2, j = u & 3;
    int s = offs[n], e = eoff[n];
    float dn = dinv[n];
    float a0 = 0.f, a1 = 0.f, a2 = 0.f, a3 = 0.f, a4 = 0.f, a5 = 0.f;
    for (int i = s + 4 * j; i < e; i += 16) {
        int4 q = *(const int4*)(edges + i);
        int4 nq;
        { u32 wd = (u32)q.x; u32 r = wd & 0xFFFFu; float wn = h2f_bits(wd >> 16) * dn * dinv[r];
          nq.x = (int)(r | (f2h_bits(wn) << 16)); gath(xpad, r, wn, a0, a1, a2, a3, a4, a5); }
        { u32 wd = (u32)q.y; u32 r = wd & 0xFFFFu; float wn = h2f_bits(wd >> 16) * dn * dinv[r];
          nq.y = (int)(r | (f2h_bits(wn) << 16)); gath(xpad, r, wn, a0, a1, a2, a3, a4, a5); }
        { u32 wd = (u32)q.z; u32 r = wd & 0xFFFFu; float wn = h2f_bits(wd >> 16) * dn * dinv[r];
          nq.z = (int)(r | (f2h_bits(wn) << 16)); gath(xpad, r, wn, a0, a1, a2, a3, a4, a5); }
        { u32 wd = (u32)q.w; u32 r = wd & 0xFFFFu; float wn = h2f_bits(wd >> 16) * dn * dinv[r];
          nq.w = (int)(r | (f2h_bits(wn) << 16)); gath(xpad, r, wn, a0, a1, a2, a3, a4, a5); }
        *(int4*)(edges + i) = nq;
    }
#pragma unroll
    for (int d = 1; d < 4; d <<= 1) {
        a0 += __shfl_xor(a0, d); a1 += __shfl_xor(a1, d); a2 += __shfl_xor(a2, d);
        a3 += __shfl_xor(a3, d); a4 += __shfl_xor(a4, d); a5 += __shfl_xor(a5, d);
    }
    float v0 = j == 0 ? a0 : j == 1 ? a2 : j == 2 ? a4 : 0.f;
    float v1 = j == 0 ? a1 : j == 1 ? a3 : j == 2 ? a5 : 0.f;
    ((u32*)xnext)[(size_t)n * 4 + j] = pack2(v0, v1);
}

__device__ __forceinline__ void final_unit(int u, const int* __restrict__ offs,
        const int* __restrict__ eoff, const u32* __restrict__ edges,
        const f16* __restrict__ xprev, const float* __restrict__ y0,
        float* __restrict__ out) {
    int n = u >> 2, j = u & 3;
    int s = offs[n], e = eoff[n];
    float a0 = 0.f, a1 = 0.f, a2 = 0.f, a3 = 0.f, a4 = 0.f, a5 = 0.f;
    for (int i = s + 4 * j; i < e; i += 16) {
        int4 q = *(const int4*)(edges + i);
        { u32 wd = (u32)q.x; gath(xprev, wd & 0xFFFFu, h2f_bits(wd >> 16), a0, a1, a2, a3, a4, a5); }
        { u32 wd = (u32)q.y; gath(xprev, wd & 0xFFFFu, h2f_bits(wd >> 16), a0, a1, a2, a3, a4, a5); }
        { u32 wd = (u32)q.z; gath(xprev, wd & 0xFFFFu, h2f_bits(wd >> 16), a0, a1, a2, a3, a4, a5); }
        { u32 wd = (u32)q.w; gath(xprev, wd & 0xFFFFu, h2f_bits(wd >> 16), a0, a1, a2, a3, a4, a5); }
    }
#pragma unroll
    for (int d = 1; d < 4; d <<= 1) {
        a0 += __shfl_xor(a0, d); a1 += __shfl_xor(a1, d); a2 += __shfl_xor(a2, d);
        a3 += __shfl_xor(a3, d); a4 += __shfl_xor(a4, d); a5 += __shfl_xor(a5, d);
    }
    if (j < 3) {
        float mv = (j == 0 ? a0 : j == 1 ? a1 : a2) + y0[(size_t)n * 32 + j];
        float sv = (j == 0 ? a3 : j == 1 ? a4 : a5) + y0[(size_t)n * 32 + 3 + j];
        out[n * ADIM + j] = tanhf(mv);
        out[NN * ADIM + n * ADIM + j] = expf(2.f * tanhf(sv));
    }
}

__device__ void dense_body(int bb, int t, const float* __restrict__ x,
                           const f16* __restrict__ xs, const float* __restrict__ W1T,
                           const float* __restrict__ b1, const float* __restrict__ W2T,
                           float* __restrict__ pacc) {
    int c = bb & (NCH - 1);
    int n = (bb >> 2) * 256 + t;
    if (n >= NN) return;
    float in[30];
    {
        const float* xr = x + (size_t)n * 6;
        float2 v0 = *(const float2*)xr;
        float2 v1 = *(const float2*)(xr + 2);
        float2 v2 = *(const float2*)(xr + 4);
        in[0] = v0.x; in[1] = v0.y; in[2] = v1.x;
        in[3] = v1.y; in[4] = v2.x; in[5] = v2.y;
    }
#pragma unroll
    for (int k = 0; k < 4; ++k) {
        f16x8 v = *(const f16x8*)(xs + (size_t)k * NN8 + (size_t)n * 8);
#pragma unroll
        for (int cc = 0; cc < 6; ++cc) in[6 + k * 6 + cc] = (float)v[cc];
    }
    float acc[32];
#pragma unroll
    for (int o = 0; o < 32; ++o) acc[o] = 0.f;
    int f0 = c * (FH / NCH);
#pragma unroll 2
    for (int fi = 0; fi < FH / NCH; ++fi) {
        int f = f0 + fi;
        const float* w1c = W1T + f * 30;
        float h = b1[f];
#pragma unroll
        for (int i = 0; i < 30; ++i) h = fmaf(in[i], w1c[i], h);
        h = h > 0.f ? h : 0.f;
        const float* w2c = W2T + f * 30;
#pragma unroll
        for (int o = 0; o < 30; ++o) acc[o] = fmaf(h, w2c[o], acc[o]);
    }
    float* pr = pacc + ((size_t)c * NN + n) * 32;
#pragma unroll
    for (int o4 = 0; o4 < 8; ++o4)
        *(float4*)(pr + o4 * 4) = make_float4(acc[o4 * 4], acc[o4 * 4 + 1],
                                              acc[o4 * 4 + 2], acc[o4 * 4 + 3]);
}

__device__ __forceinline__ void reduce_unit(int n, const float* __restrict__ pacc,
                                            const float* __restrict__ b2,
                                            float* __restrict__ ys, f16* __restrict__ y4h) {
    float acc[32];
#pragma unroll
    for (int o = 0; o < 32; ++o) acc[o] = 0.f;
#pragma unroll
    for (int c = 0; c < NCH; ++c) {
        const float* pr = pacc + ((size_t)c * NN + n) * 32;
#pragma unroll
        for (int o4 = 0; o4 < 8; ++o4) {
            float4 v = *(const float4*)(pr + o4 * 4);
            acc[o4 * 4 + 0] += v.x; acc[o4 * 4 + 1] += v.y;
            acc[o4 * 4 + 2] += v.z; acc[o4 * 4 + 3] += v.w;
        }
    }
#pragma unroll
    for (int o = 0; o < 6; ++o) acc[o] += b2[o];
    float* yr = ys + (size_t)n * 32;
#pragma unroll
    for (int o4 = 0; o4 < 6; ++o4)
        *(float4*)(yr + o4 * 4) = make_float4(acc[o4 * 4], acc[o4 * 4 + 1],
                                              acc[o4 * 4 + 2], acc[o4 * 4 + 3]);
    u32* yh = (u32*)(y4h + (size_t)n * 8);
    yh[0] = pack2(acc[24], acc[25]);
    yh[1] = pack2(acc[26], acc[27]);
    yh[2] = pack2(acc[28], acc[29]);
}

// ================= mega cooperative kernel =================

__global__ __launch_bounds__(256, 3) void mega_kernel(Params p) {
    cg::grid_group grid = cg::this_grid();
    __shared__ u32 sm[7168];   // 28.7 KB scratch (partition/csr phases)
    int t = threadIdx.x, blk = blockIdx.x;
    int gtid = blk * 256 + t;
    const int GB = GRID_G * 256;

    // P0: clear ghist + pad_x + weight transpose
    for (int i = gtid; i < NBKT; i += GB) p.ghist[i] = 0;
    padx_body(gtid, GB, p.x, p.xpad, p.W1, p.W2, p.W1T, p.W2T);
    grid.sync();
    // P1: histogram
    if (blk < NPB) hist_body(blk, t, p.col, p.ghist, sm);
    grid.sync();
    // P2: scan
    if (blk == 0) scan_body(t, p.ghist, p.bbase, p.bcur, sm);
    grid.sync();
    // P3: partition
    if (blk < NPB) partition_body(blk, t, p.row, p.col, p.ew, p.bcur, p.etmp, sm);
    grid.sync();
    // P4: per-bucket CSR
    if (blk < NBKT) csr_body(blk, t, p.bbase, p.etmp, p.edges, p.offs, p.eoff, p.dinv, sm);
    grid.sync();
    // P5: hop1 + norm
    for (int u = gtid; u < NN * 4; u += GB)
        hopnorm_unit(u, p.offs, p.eoff, p.edges, p.dinv, p.xpad, p.xs);
    grid.sync();
    // P6-P8: layer-1 hops 2..4
    for (int k = 2; k <= KH; ++k) {
        for (int u = gtid; u < NN * 4; u += GB)
            hop_unit(u, p.offs, p.eoff, p.edges,
                     p.xs + (size_t)(k - 2) * NN8, nullptr, p.xs + (size_t)(k - 1) * NN8);
        grid.sync();
    }
    // P9: fused dense (f-chunked)
    for (int bb = blk; bb < NDB * NCH; bb += GRID_G)
        dense_body(bb, t, p.x, p.xs, p.W1T, p.b1, p.W2T, p.pacc);
    grid.sync();
    // P10: reduce partials
    for (int n = gtid; n < NN; n += GB) reduce_unit(n, p.pacc, p.b2, p.ys, p.y4h);
    grid.sync();
    // P11-P13: layer-2 Horner hops
    for (int u = gtid; u < NN * 4; u += GB)
        hop_unit(u, p.offs, p.eoff, p.edges, p.y4h, p.ys + 18, p.za);
    grid.sync();
    for (int u = gtid; u < NN * 4; u += GB)
        hop_unit(u, p.offs, p.eoff, p.edges, p.za, p.ys + 12, p.zb);
    grid.sync();
    for (int u = gtid; u < NN * 4; u += GB)
        hop_unit(u, p.offs, p.eoff, p.edges, p.zb, p.ys + 6, p.za);
    grid.sync();
    // P14: final hop + tanh/exp
    for (int u = gtid; u < NN * 4; u += GB)
        final_unit(u, p.offs, p.eoff, p.edges, p.za, p.ys, p.out);
}

// ================= standalone fallback kernels =================

__global__ void k_clearpad(Params p) {
    int gtid = blockIdx.x * 256 + threadIdx.x;
    int gsz = gridDim.x * 256;
    for (int i = gtid; i < NBKT; i += gsz) p.ghist[i] = 0;
    padx_body(gtid, gsz, p.x, p.xpad, p.W1, p.W2, p.W1T, p.W2T);
}
__global__ void k_hist(Params p) {
    __shared__ u32 sm[256];
    hist_body(blockIdx.x, threadIdx.x, p.col, p.ghist, sm);
}
__global__ void k_scan(Params p) {
    __shared__ u32 sm[256];
    scan_body(threadIdx.x, p.ghist, p.bbase, p.bcur, sm);
}
__global__ __launch_bounds__(256) void k_partition(Params p) {
    __shared__ u32 sm[6988];
    partition_body(blockIdx.x, threadIdx.x, p.row, p.col, p.ew, p.bcur, p.etmp, sm);
}
__global__ __launch_bounds__(256) void k_csr(Params p) {
    __shared__ u32 sm[7168];
    csr_body(blockIdx.x, threadIdx.x, p.bbase, p.etmp, p.edges, p.offs, p.eoff, p.dinv, sm);
}
__global__ void k_hopnorm(Params p) {
    int u = blockIdx.x * 256 + threadIdx.x;
    if (u < NN * 4) hopnorm_unit(u, p.offs, p.eoff, p.edges, p.dinv, p.xpad, p.xs);
}
__global__ void k_hop(Params p, const f16* xprev, const float* yadd, f16* xnext) {
    int u = blockIdx.x * 256 + threadIdx.x;
    if (u < NN * 4) hop_unit(u, p.offs, p.eoff, p.edges, xprev, yadd, xnext);
}
__global__ __launch_bounds__(256) void k_dense(Params p) {
    dense_body(blockIdx.x, threadIdx.x, p.x, p.xs, p.W1T, p.b1, p.W2T, p.pacc);
}
__global__ void k_reduce(Params p) {
    int n = blockIdx.x * 256 + threadIdx.x;
    if (n < NN) reduce_unit(n, p.pacc, p.b2, p.ys, p.y4h);
}
__global__ void k_final(Params p) {
    int u = blockIdx.x * 256 + threadIdx.x;
    if (u < NN * 4) final_unit(u, p.offs, p.eoff, p.edges, p.za, p.ys, p.out);
}

extern "C" void kernel_launch(void* const* d_in, const int* in_sizes, int n_in,
                              void* d_out, int out_size, void* d_ws, size_t ws_size,
                              hipStream_t stream) {
    Params p;
    p.x  = (const float*)d_in[0];
    const int* ei = (const int*)d_in[1];
    p.row = ei;
    p.col = ei + NE;
    p.ew = (const float*)d_in[2];
    p.W1 = (const float*)d_in[3];
    p.b1 = (const float*)d_in[4];
    p.W2 = (const float*)d_in[5];
    p.b2 = (const float*)d_in[6];
    p.out = (float*)d_out;

    p.xpad = (f16*)d_ws;                       // NN8
    p.xs   = p.xpad + NN8;                     // KH*NN8
    p.y4h  = p.xs + (size_t)KH * NN8;          // NN8
    p.za   = p.y4h + NN8;                      // NN8
    p.zb   = p.za + NN8;                       // NN8
    p.ys   = (float*)(p.zb + NN8);             // NN*32
    p.pacc = p.ys + (size_t)NN * 32;           // NCH*NN*32
    p.W1T  = p.pacc + (size_t)NCH * NN * 32;   // 3840
    p.W2T  = p.W1T + 30 * FH;                  // 3840
    p.etmp = (Edge*)(p.W2T + 30 * FH);         // NE
    p.edges = (u32*)(p.etmp + NE);             // NEPAD
    p.ghist = p.edges + NEPAD;                 // NBKT
    p.bbase = p.ghist + NBKT;                  // NBKT+1
    p.bcur  = p.bbase + NBKT + 1;              // NBKT
    p.offs  = (int*)(p.bcur + NBKT);           // NN
    p.eoff  = p.offs + NN;                     // NN
    p.dinv  = (float*)(p.eoff + NN);           // NN

    void* args[] = { &p };
    hipError_t err = hipLaunchCooperativeKernel((const void*)mega_kernel,
                                                dim3(GRID_G), dim3(256), args, 0, stream);
    if (err != hipSuccess) {
        (void)hipGetLastError();   // clear error state; run fallback path
        const int B = 256;
        const int gHop = (NN * 4 + B - 1) / B;
        const int gPad = (NN8 + B - 1) / B;
        k_clearpad<<<gPad, B, 0, stream>>>(p);
        k_hist<<<NPB, B, 0, stream>>>(p);
        k_scan<<<1, B, 0, stream>>>(p);
        k_partition<<<NPB, B, 0, stream>>>(p);
        k_csr<<<NBKT, B, 0, stream>>>(p);
        k_hopnorm<<<gHop, B, 0, stream>>>(p);
        for (int k = 2; k <= KH; ++k)
            k_hop<<<gHop, B, 0, stream>>>(p, p.xs + (size_t)(k - 2) * NN8, nullptr,
                                          p.xs + (size_t)(k - 1) * NN8);
        k_dense<<<NDB * NCH, B, 0, stream>>>(p);
        k_reduce<<<NDB, B, 0, stream>>>(p);
        k_hop<<<gHop, B, 0, stream>>>(p, p.y4h, p.ys + 18, p.za);
        k_hop<<<gHop, B, 0, stream>>>(p, p.za, p.ys + 12, p.zb);
        k_hop<<<gHop, B, 0, stream>>>(p, p.zb, p.ys + 6, p.za);
        k_final<<<gHop, B, 0, stream>>>(p);
    }
}

// Round 15
// 170.235 us; speedup vs baseline: 8.0988x; 8.0988x over previous
//
#include <hip/hip_runtime.h>

#define NN 50000
#define NE 800000
#define KH 4
#define FIN 6
#define FH 128
#define FO 6
#define ADIM 3
#define NN8 (NN * 8)
#define NBKT 196        // ceil(NN / 256) buckets of 256 node ids
#define EPB 2048        // edges per partition block
#define NPB 391         // ceil(NE / EPB)
#define CAP 6144        // LDS staging capacity per bucket (u32 edges, 24 KB)
#define ROWMASK 0xFFFFFu
#define NEPAD (NE + NBKT * 1024)  // padded edge capacity (pad-to-4 per node)
#define DRB 782         // dense_reduce blocks: ceil(NN/64)

typedef unsigned int u32;
typedef _Float16 f16;
typedef f16 f16x8 __attribute__((ext_vector_type(8)));

struct __align__(8) Edge { u32 r; float w; };   // staging record (20-bit row meta)

__device__ __forceinline__ float h2f_bits(u32 hb) {
    union { unsigned short us; f16 h; } c; c.us = (unsigned short)hb; return (float)c.h;
}
__device__ __forceinline__ u32 f2h_bits(float f) {
    union { unsigned short us; f16 h; } c; c.h = (f16)f; return (u32)c.us;
}
__device__ __forceinline__ u32 pack2(float a, float b) {
    return f2h_bits(a) | (f2h_bits(b) << 16);
}

// ---------------- K1: bucket histogram (col >> 8) ----------------
__global__ void bucket_hist(const int* __restrict__ col, u32* __restrict__ ghist) {
    __shared__ u32 h[NBKT];
    for (int t = threadIdx.x; t < NBKT; t += 256) h[t] = 0;
    __syncthreads();
    int base = blockIdx.x * EPB;
#pragma unroll
    for (int i = 0; i < EPB / 256; ++i) {
        int e = base + i * 256 + threadIdx.x;
        if (e < NE) atomicAdd(&h[((u32)col[e]) >> 8], 1u);
    }
    __syncthreads();
    for (int t = threadIdx.x; t < NBKT; t += 256)
        if (h[t]) atomicAdd(&ghist[t], h[t]);
}

// ---------------- K2: scan bucket counts -> bases/cursors ----------------
__global__ void bucket_scan(const u32* __restrict__ ghist, u32* __restrict__ bbase,
                            u32* __restrict__ bcur) {
    __shared__ u32 sh[256];
    int t = threadIdx.x;
    u32 v = (t < NBKT) ? ghist[t] : 0;
    sh[t] = v;
    __syncthreads();
    for (int off = 1; off < 256; off <<= 1) {
        u32 u = (t >= off) ? sh[t - off] : 0;
        __syncthreads();
        sh[t] += u;
        __syncthreads();
    }
    if (t < NBKT) { bbase[t] = sh[t] - v; bcur[t] = sh[t] - v; }
    if (t == NBKT - 1) bbase[NBKT] = sh[t];
}

// ---------------- K3: partition edges into bucket-grouped etmp (LDS-staged) ----------------
__global__ __launch_bounds__(256) void partition_kernel(
        const int* __restrict__ row, const int* __restrict__ col,
        const float* __restrict__ w, u32* __restrict__ bcur,
        Edge* __restrict__ etmp) {
    __shared__ u32 hcnt[NBKT];
    __shared__ u32 hloc[NBKT];
    __shared__ u32 hglb[NBKT];
    __shared__ u32 smeta[EPB];
    __shared__ float swt[EPB];
    __shared__ u32 sgid[EPB];
    __shared__ u32 sc[256];
    for (int t = threadIdx.x; t < NBKT; t += 256) hcnt[t] = 0;
    __syncthreads();
    int base = blockIdx.x * EPB;
    u32 m_[8]; float w_[8]; u32 b_[8]; u32 rk_[8]; int v_[8];
#pragma unroll
    for (int i = 0; i < 8; ++i) {
        int e = base + i * 256 + threadIdx.x;
        v_[i] = e < NE;
        if (v_[i]) {
            u32 c = (u32)col[e];
            u32 r = (u32)row[e];
            b_[i] = c >> 8;
            m_[i] = ((c & 255u) << 20) | r;
            w_[i] = w[e];
            rk_[i] = atomicAdd(&hcnt[b_[i]], 1u);
        }
    }
    __syncthreads();
    {   // exclusive scan of hcnt -> hloc
        int t = threadIdx.x;
        u32 v = (t < NBKT) ? hcnt[t] : 0;
        sc[t] = v;
        __syncthreads();
        for (int off = 1; off < 256; off <<= 1) {
            u32 u = (t >= off) ? sc[t - off] : 0;
            __syncthreads();
            sc[t] += u;
            __syncthreads();
        }
        if (t < NBKT) hloc[t] = sc[t] - v;
    }
    __syncthreads();
    for (int t = threadIdx.x; t < NBKT; t += 256)
        if (hcnt[t]) hglb[t] = atomicAdd(&bcur[t], hcnt[t]);
    __syncthreads();
#pragma unroll
    for (int i = 0; i < 8; ++i) if (v_[i]) {
        u32 slot = hloc[b_[i]] + rk_[i];
        smeta[slot] = m_[i];
        swt[slot] = w_[i];
        sgid[slot] = hglb[b_[i]] + rk_[i];
    }
    __syncthreads();
    int tot = NE - base; if (tot > EPB) tot = EPB;
    for (int s = threadIdx.x; s < tot; s += 256) {
        Edge ed; ed.r = smeta[s]; ed.w = swt[s];
        etmp[sgid[s]] = ed;
    }
}

// ---------------- K4: per-bucket CSR build, 4B packed edges, pad-to-4 segments ----------------
__global__ __launch_bounds__(256) void bucket_csr(
        const u32* __restrict__ bbase, const Edge* __restrict__ etmp,
        u32* __restrict__ edges, int* __restrict__ offs, int* __restrict__ eoff,
        float* __restrict__ dinv) {
    int b = blockIdx.x;
    int t = threadIdx.x;
    u32 s = bbase[b], e = bbase[b + 1];
    int cnt = (int)(e - s);
    u32 rb = s + (u32)b * 1024u;         // padded region base (each bucket +1024 slack)
    int node0 = b << 8;
    int nloc = NN - node0; if (nloc > 256) nloc = 256;
    __shared__ u32 ncnt[256];
    __shared__ float nsum[256];
    __shared__ u32 ncur[256];
    __shared__ u32 sc[256];
    __shared__ u32 stage[CAP];   // 24 KB
    ncnt[t] = 0; nsum[t] = 0.f;
    __syncthreads();
    for (int i = t; i < cnt; i += 256) {
        Edge ed = etmp[s + i];
        u32 cl = ed.r >> 20;
        atomicAdd(&ncnt[cl], 1u);
        atomicAdd(&nsum[cl], ed.w);
    }
    __syncthreads();
    u32 v = ncnt[t];
    u32 pv = (v + 3u) & ~3u;             // pad each node's segment to multiple of 4
    sc[t] = pv;
    __syncthreads();
    for (int off = 1; off < 256; off <<= 1) {
        u32 u = (t >= off) ? sc[t - off] : 0;
        __syncthreads();
        sc[t] += u;
        __syncthreads();
    }
    u32 excl = sc[t] - pv;
    u32 ptot = sc[255];
    ncur[t] = excl;
    if (t < nloc) {
        offs[node0 + t] = (int)(rb + excl);
        eoff[node0 + t] = (int)(rb + excl + pv);
        float d = nsum[t];
        dinv[node0 + t] = d > 0.f ? rsqrtf(d) : 0.f;
    }
    __syncthreads();
    for (int i = t; i < cnt; i += 256) {
        Edge ed = etmp[s + i];
        u32 cl = ed.r >> 20;
        u32 slot = atomicAdd(&ncur[cl], 1u);
        u32 pw = (ed.r & ROWMASK) | (f2h_bits(ed.w) << 16);   // row fits 16 bits (NN<65536)
        if (slot < CAP) stage[slot] = pw;
        else edges[rb + slot] = pw;
    }
    if (t < nloc) {                      // zero-edge pads
        for (u32 slot = excl + v; slot < excl + pv; ++slot) {
            if (slot < CAP) stage[slot] = 0u;
            else edges[rb + slot] = 0u;
        }
    }
    __syncthreads();
    int lim = (int)(ptot < CAP ? ptot : CAP);
    for (int i = t; i < lim; i += 256) edges[rb + i] = stage[i];
}

// ---------------- pad/convert x rows to f16 stride 8; weight transposes; ghist clear ----------------
__global__ void pad_x(const float* __restrict__ x, f16* __restrict__ xpad,
                      const float* __restrict__ W1, const float* __restrict__ W2,
                      float* __restrict__ W1T, float* __restrict__ W2T,
                      u32* __restrict__ ghist) {
    int t = blockIdx.x * blockDim.x + threadIdx.x;
    if (t < NBKT) ghist[t] = 0;
    if (t < 30 * FH) {
        int f = t / 30, i = t - f * 30;
        W1T[t] = W1[i * FH + f];
        int k = i / 6, a = i - k * 6;
        W2T[t] = W2[((size_t)k * FH + f) * FO + a];
    }
    if (t >= NN8) return;
    int n = t >> 3, c = t & 7;
    xpad[t] = (c < 6) ? (f16)x[n * 6 + c] : (f16)0.f;
}

// ---------------- gather: one dwordx4 = 8 f16, use 6 ----------------
__device__ __forceinline__ void gath(const f16* __restrict__ xp, u32 r, float w,
                                     float& a0, float& a1, float& a2,
                                     float& a3, float& a4, float& a5) {
    f16x8 v = *(const f16x8*)(xp + (size_t)r * 8);
    a0 += w * (float)v[0]; a1 += w * (float)v[1]; a2 += w * (float)v[2];
    a3 += w * (float)v[3]; a4 += w * (float)v[4]; a5 += w * (float)v[5];
}

#define HOP_HEAD \
    int t = blockIdx.x * blockDim.x + threadIdx.x; \
    int n = t >> 2, j = t & 3; \
    if (n >= NN) return; \
    int s = offs[n], e = eoff[n]; \
    float a0 = 0.f, a1 = 0.f, a2 = 0.f, a3 = 0.f, a4 = 0.f, a5 = 0.f;

#define HOP_REDUCE \
    _Pragma("unroll") \
    for (int d = 1; d < 4; d <<= 1) { \
        a0 += __shfl_xor(a0, d); a1 += __shfl_xor(a1, d); a2 += __shfl_xor(a2, d); \
        a3 += __shfl_xor(a3, d); a4 += __shfl_xor(a4, d); a5 += __shfl_xor(a5, d); \
    }

// ---------------- hop: 4 lanes/node, 4 edges per int4; xnext(f16,8) = yadd + A*xprev ----------------
__global__ void hop4(const int* __restrict__ offs, const int* __restrict__ eoff,
                     const u32* __restrict__ edges,
                     const f16* __restrict__ xprev, const float* __restrict__ yadd,
                     f16* __restrict__ xnext) {
    HOP_HEAD
    for (int i = s + 4 * j; i < e; i += 16) {
        int4 q = *(const int4*)(edges + i);
        { u32 wd = (u32)q.x; gath(xprev, wd & 0xFFFFu, h2f_bits(wd >> 16), a0, a1, a2, a3, a4, a5); }
        { u32 wd = (u32)q.y; gath(xprev, wd & 0xFFFFu, h2f_bits(wd >> 16), a0, a1, a2, a3, a4, a5); }
        { u32 wd = (u32)q.z; gath(xprev, wd & 0xFFFFu, h2f_bits(wd >> 16), a0, a1, a2, a3, a4, a5); }
        { u32 wd = (u32)q.w; gath(xprev, wd & 0xFFFFu, h2f_bits(wd >> 16), a0, a1, a2, a3, a4, a5); }
    }
    HOP_REDUCE
    float v0 = j == 0 ? a0 : j == 1 ? a2 : j == 2 ? a4 : 0.f;
    float v1 = j == 0 ? a1 : j == 1 ? a3 : j == 2 ? a5 : 0.f;
    if (yadd && j < 3) {
        v0 += yadd[(size_t)n * 32 + 2 * j];
        v1 += yadd[(size_t)n * 32 + 2 * j + 1];
    }
    ((u32*)xnext)[(size_t)n * 4 + j] = pack2(v0, v1);
}

// ---------------- hop variant: normalize-in-place + first hop (gathers xpad) ----------------
__global__ void hop4_norm(const int* __restrict__ offs, const int* __restrict__ eoff,
                          u32* __restrict__ edges,
                          const float* __restrict__ dinv, const f16* __restrict__ xpad,
                          f16* __restrict__ xnext) {
    HOP_HEAD
    float dn = dinv[n];
    for (int i = s + 4 * j; i < e; i += 16) {
        int4 q = *(const int4*)(edges + i);
        int4 nq;
        { u32 wd = (u32)q.x; u32 r = wd & 0xFFFFu; float wn = h2f_bits(wd >> 16) * dn * dinv[r];
          nq.x = (int)(r | (f2h_bits(wn) << 16)); gath(xpad, r, wn, a0, a1, a2, a3, a4, a5); }
        { u32 wd = (u32)q.y; u32 r = wd & 0xFFFFu; float wn = h2f_bits(wd >> 16) * dn * dinv[r];
          nq.y = (int)(r | (f2h_bits(wn) << 16)); gath(xpad, r, wn, a0, a1, a2, a3, a4, a5); }
        { u32 wd = (u32)q.z; u32 r = wd & 0xFFFFu; float wn = h2f_bits(wd >> 16) * dn * dinv[r];
          nq.z = (int)(r | (f2h_bits(wn) << 16)); gath(xpad, r, wn, a0, a1, a2, a3, a4, a5); }
        { u32 wd = (u32)q.w; u32 r = wd & 0xFFFFu; float wn = h2f_bits(wd >> 16) * dn * dinv[r];
          nq.w = (int)(r | (f2h_bits(wn) << 16)); gath(xpad, r, wn, a0, a1, a2, a3, a4, a5); }
        *(int4*)(edges + i) = nq;        // persist normalized weights
    }
    HOP_REDUCE
    float v0 = j == 0 ? a0 : j == 1 ? a2 : j == 2 ? a4 : 0.f;
    float v1 = j == 0 ? a1 : j == 1 ? a3 : j == 2 ? a5 : 0.f;
    ((u32*)xnext)[(size_t)n * 4 + j] = pack2(v0, v1);
}

// ---------------- final hop fused with tanh/exp finalize ----------------
__global__ void hop4_final(const int* __restrict__ offs, const int* __restrict__ eoff,
                           const u32* __restrict__ edges,
                           const f16* __restrict__ xprev, const float* __restrict__ y0,
                           float* __restrict__ out) {
    HOP_HEAD
    for (int i = s + 4 * j; i < e; i += 16) {
        int4 q = *(const int4*)(edges + i);
        { u32 wd = (u32)q.x; gath(xprev, wd & 0xFFFFu, h2f_bits(wd >> 16), a0, a1, a2, a3, a4, a5); }
        { u32 wd = (u32)q.y; gath(xprev, wd & 0xFFFFu, h2f_bits(wd >> 16), a0, a1, a2, a3, a4, a5); }
        { u32 wd = (u32)q.z; gath(xprev, wd & 0xFFFFu, h2f_bits(wd >> 16), a0, a1, a2, a3, a4, a5); }
        { u32 wd = (u32)q.w; gath(xprev, wd & 0xFFFFu, h2f_bits(wd >> 16), a0, a1, a2, a3, a4, a5); }
    }
    HOP_REDUCE
    if (j < 3) {
        float mv = (j == 0 ? a0 : j == 1 ? a1 : a2) + y0[(size_t)n * 32 + j];
        float sv = (j == 0 ? a3 : j == 1 ? a4 : a5) + y0[(size_t)n * 32 + 3 + j];
        out[n * ADIM + j] = tanhf(mv);
        out[NN * ADIM + n * ADIM + j] = expf(2.f * tanhf(sv));
    }
}

// ---------------- fused dense+reduce: block = 64 nodes x 4 f-chunks; LDS partials ----------------
// thread (c = t>>6, nl = t&63): partial over f in [c*32, c*32+32) for node blk*64+nl.
// LDS stride 33 -> conflict-free. Reduce half: thread (nl2 = t>>2, q = t&3) sums 4 chunks
// for outputs [q*8, q*8+8), adds b2, writes ys (fp32, o<24) / y4h (f16, o 24..29).
__global__ __launch_bounds__(256) void dense_reduce_kernel(
        const float* __restrict__ x, const f16* __restrict__ xs,
        const float* __restrict__ W1T, const float* __restrict__ b1,
        const float* __restrict__ W2T, const float* __restrict__ b2,
        float* __restrict__ ys, f16* __restrict__ y4h) {
    __shared__ float red[256 * 33];   // 33.8 KB
    int t = threadIdx.x;
    int c = t >> 6, nl = t & 63;
    int n = blockIdx.x * 64 + nl;
    float acc[30];
#pragma unroll
    for (int o = 0; o < 30; ++o) acc[o] = 0.f;
    if (n < NN) {
        float in[30];
        {
            const float* xr = x + (size_t)n * 6;
            float2 v0 = *(const float2*)xr;
            float2 v1 = *(const float2*)(xr + 2);
            float2 v2 = *(const float2*)(xr + 4);
            in[0] = v0.x; in[1] = v0.y; in[2] = v1.x;
            in[3] = v1.y; in[4] = v2.x; in[5] = v2.y;
        }
#pragma unroll
        for (int k = 0; k < 4; ++k) {
            f16x8 v = *(const f16x8*)(xs + (size_t)k * NN8 + (size_t)n * 8);
#pragma unroll
            for (int cc = 0; cc < 6; ++cc) in[6 + k * 6 + cc] = (float)v[cc];
        }
        int f0 = c * (FH / 4);
#pragma unroll 2
        for (int fi = 0; fi < FH / 4; ++fi) {
            int f = f0 + fi;
            const float* w1c = W1T + f * 30;   // wave-uniform -> scalar loads
            float h = b1[f];
#pragma unroll
            for (int i = 0; i < 30; ++i) h = fmaf(in[i], w1c[i], h);
            h = h > 0.f ? h : 0.f;
            const float* w2c = W2T + f * 30;
#pragma unroll
            for (int o = 0; o < 30; ++o) acc[o] = fmaf(h, w2c[o], acc[o]);
        }
    }
    float* my = &red[t * 33];
#pragma unroll
    for (int o = 0; o < 30; ++o) my[o] = acc[o];
    __syncthreads();
    int nl2 = t >> 2, q = t & 3;
    int n2 = blockIdx.x * 64 + nl2;
    if (n2 >= NN) return;
    float r[8];
#pragma unroll
    for (int i = 0; i < 8; ++i) {
        int o = q * 8 + i;
        float s = 0.f;
        if (o < 30) {
#pragma unroll
            for (int cc = 0; cc < 4; ++cc) s += red[(cc * 64 + nl2) * 33 + o];
            if (o < 6) s += b2[o];
        }
        r[i] = s;
    }
    if (q < 3) {
        float* yr = ys + (size_t)n2 * 32 + q * 8;
        *(float4*)yr = make_float4(r[0], r[1], r[2], r[3]);
        *(float4*)(yr + 4) = make_float4(r[4], r[5], r[6], r[7]);
    } else {
        u32* yh = (u32*)(y4h + (size_t)n2 * 8);
        yh[0] = pack2(r[0], r[1]);
        yh[1] = pack2(r[2], r[3]);
        yh[2] = pack2(r[4], r[5]);
    }
}

extern "C" void kernel_launch(void* const* d_in, const int* in_sizes, int n_in,
                              void* d_out, int out_size, void* d_ws, size_t ws_size,
                              hipStream_t stream) {
    const float* x  = (const float*)d_in[0];
    const int*   ei = (const int*)d_in[1];
    const float* ew = (const float*)d_in[2];
    const float* W1 = (const float*)d_in[3];
    const float* b1 = (const float*)d_in[4];
    const float* W2 = (const float*)d_in[5];
    const float* b2 = (const float*)d_in[6];
    float* out = (float*)d_out;

    const int* row = ei;
    const int* col = ei + NE;

    // workspace layout: f16 planes first (16B-aligned, sizes multiple of 16B)
    f16*   xpad  = (f16*)d_ws;                  // NN8
    f16*   xs    = xpad + NN8;                  // KH*NN8
    f16*   y4h   = xs + (size_t)KH * NN8;       // NN8
    f16*   za    = y4h + NN8;                   // NN8
    f16*   zb    = za + NN8;                    // NN8
    float* ys    = (float*)(zb + NN8);          // NN*32 fp32
    float* W1T   = ys + (size_t)NN * 32;        // 3840
    float* W2T   = W1T + 30 * FH;               // 3840
    Edge*  etmp  = (Edge*)(W2T + 30 * FH);      // NE (8B)
    u32*   edges = (u32*)(etmp + NE);           // NEPAD (4B packed)
    u32*   ghist = edges + NEPAD;               // NBKT
    u32*   bbase = ghist + NBKT;                // NBKT+1
    u32*   bcur  = bbase + NBKT + 1;            // NBKT
    int*   offs  = (int*)(bcur + NBKT);         // NN
    int*   eoff  = offs + NN;                   // NN
    float* dinv  = (float*)(eoff + NN);         // NN

    const int B = 256;
    const int gHop = (NN * 4 + B - 1) / B;
    const int gPad = (NN8 + B - 1) / B;

    // ---- CSR build (ghist clear + weight transpose folded into pad_x) ----
    pad_x<<<gPad, B, 0, stream>>>(x, xpad, W1, W2, W1T, W2T, ghist);
    bucket_hist<<<NPB, B, 0, stream>>>(col, ghist);
    bucket_scan<<<1, B, 0, stream>>>(ghist, bbase, bcur);
    partition_kernel<<<NPB, B, 0, stream>>>(row, col, ew, bcur, etmp);
    bucket_csr<<<NBKT, B, 0, stream>>>(bbase, etmp, edges, offs, eoff, dinv);

    // ---- layer 1: hops (hop 1 fuses normalization) ----
    hop4_norm<<<gHop, B, 0, stream>>>(offs, eoff, edges, dinv, xpad, xs);
    for (int k = 2; k <= KH; ++k)
        hop4<<<gHop, B, 0, stream>>>(offs, eoff, edges,
                                     xs + (size_t)(k - 2) * NN8, nullptr,
                                     xs + (size_t)(k - 1) * NN8);

    // ---- fused dense1 + relu + proj2 + reduce (LDS partials, no pacc round-trip) ----
    dense_reduce_kernel<<<DRB, B, 0, stream>>>(x, xs, W1T, b1, W2T, b2, ys, y4h);

    // ---- layer 2 Horner on 6-wide ----
    hop4<<<gHop, B, 0, stream>>>(offs, eoff, edges, y4h, ys + 18, za);
    hop4<<<gHop, B, 0, stream>>>(offs, eoff, edges, za, ys + 12, zb);
    hop4<<<gHop, B, 0, stream>>>(offs, eoff, edges, zb, ys + 6, za);
    hop4_final<<<gHop, B, 0, stream>>>(offs, eoff, edges, za, ys, out);
}

// Round 16
// 146.657 us; speedup vs baseline: 9.4009x; 1.1608x over previous
//
#include <hip/hip_runtime.h>

#define NN 50000
#define NE 800000
#define KH 4
#define FIN 6
#define FH 128
#define FO 6
#define ADIM 3
#define NN8 (NN * 8)
#define NBKT 196        // ceil(NN / 256) buckets of 256 node ids
#define EPB 2048        // edges per partition block
#define NPB 391         // ceil(NE / EPB)
#define CAP 6144        // LDS staging capacity per bucket (u32 edges, 24 KB)
#define ROWMASK 0xFFFFFu
#define NEPAD (NE + NBKT * 1024)  // padded edge capacity (pad-to-4 per node)
#define NCH 4           // f-chunks for fused dense (occupancy)
#define NDB 196         // node blocks: ceil(NN/256)

typedef unsigned int u32;
typedef _Float16 f16;
typedef f16 f16x8 __attribute__((ext_vector_type(8)));

struct __align__(8) Edge { u32 r; float w; };   // staging record (20-bit row meta)

__device__ __forceinline__ float h2f_bits(u32 hb) {
    union { unsigned short us; f16 h; } c; c.us = (unsigned short)hb; return (float)c.h;
}
__device__ __forceinline__ u32 f2h_bits(float f) {
    union { unsigned short us; f16 h; } c; c.h = (f16)f; return (u32)c.us;
}
__device__ __forceinline__ u32 pack2(float a, float b) {
    return f2h_bits(a) | (f2h_bits(b) << 16);
}

// ---------------- K1: bucket histogram (col >> 8) ----------------
__global__ void bucket_hist(const int* __restrict__ col, u32* __restrict__ ghist) {
    __shared__ u32 h[NBKT];
    for (int t = threadIdx.x; t < NBKT; t += 256) h[t] = 0;
    __syncthreads();
    int base = blockIdx.x * EPB;
#pragma unroll
    for (int i = 0; i < EPB / 256; ++i) {
        int e = base + i * 256 + threadIdx.x;
        if (e < NE) atomicAdd(&h[((u32)col[e]) >> 8], 1u);
    }
    __syncthreads();
    for (int t = threadIdx.x; t < NBKT; t += 256)
        if (h[t]) atomicAdd(&ghist[t], h[t]);
}

// ---------------- K2: scan bucket counts -> bases/cursors ----------------
__global__ void bucket_scan(const u32* __restrict__ ghist, u32* __restrict__ bbase,
                            u32* __restrict__ bcur) {
    __shared__ u32 sh[256];
    int t = threadIdx.x;
    u32 v = (t < NBKT) ? ghist[t] : 0;
    sh[t] = v;
    __syncthreads();
    for (int off = 1; off < 256; off <<= 1) {
        u32 u = (t >= off) ? sh[t - off] : 0;
        __syncthreads();
        sh[t] += u;
        __syncthreads();
    }
    if (t < NBKT) { bbase[t] = sh[t] - v; bcur[t] = sh[t] - v; }
    if (t == NBKT - 1) bbase[NBKT] = sh[t];
}

// ---------------- K3: partition edges into bucket-grouped etmp (LDS-staged) ----------------
__global__ __launch_bounds__(256) void partition_kernel(
        const int* __restrict__ row, const int* __restrict__ col,
        const float* __restrict__ w, u32* __restrict__ bcur,
        Edge* __restrict__ etmp) {
    __shared__ u32 hcnt[NBKT];
    __shared__ u32 hloc[NBKT];
    __shared__ u32 hglb[NBKT];
    __shared__ u32 smeta[EPB];
    __shared__ float swt[EPB];
    __shared__ u32 sgid[EPB];
    __shared__ u32 sc[256];
    for (int t = threadIdx.x; t < NBKT; t += 256) hcnt[t] = 0;
    __syncthreads();
    int base = blockIdx.x * EPB;
    u32 m_[8]; float w_[8]; u32 b_[8]; u32 rk_[8]; int v_[8];
#pragma unroll
    for (int i = 0; i < 8; ++i) {
        int e = base + i * 256 + threadIdx.x;
        v_[i] = e < NE;
        if (v_[i]) {
            u32 c = (u32)col[e];
            u32 r = (u32)row[e];
            b_[i] = c >> 8;
            m_[i] = ((c & 255u) << 20) | r;
            w_[i] = w[e];
            rk_[i] = atomicAdd(&hcnt[b_[i]], 1u);
        }
    }
    __syncthreads();
    {   // exclusive scan of hcnt -> hloc
        int t = threadIdx.x;
        u32 v = (t < NBKT) ? hcnt[t] : 0;
        sc[t] = v;
        __syncthreads();
        for (int off = 1; off < 256; off <<= 1) {
            u32 u = (t >= off) ? sc[t - off] : 0;
            __syncthreads();
            sc[t] += u;
            __syncthreads();
        }
        if (t < NBKT) hloc[t] = sc[t] - v;
    }
    __syncthreads();
    for (int t = threadIdx.x; t < NBKT; t += 256)
        if (hcnt[t]) hglb[t] = atomicAdd(&bcur[t], hcnt[t]);
    __syncthreads();
#pragma unroll
    for (int i = 0; i < 8; ++i) if (v_[i]) {
        u32 slot = hloc[b_[i]] + rk_[i];
        smeta[slot] = m_[i];
        swt[slot] = w_[i];
        sgid[slot] = hglb[b_[i]] + rk_[i];
    }
    __syncthreads();
    int tot = NE - base; if (tot > EPB) tot = EPB;
    for (int s = threadIdx.x; s < tot; s += 256) {
        Edge ed; ed.r = smeta[s]; ed.w = swt[s];
        etmp[sgid[s]] = ed;
    }
}

// ---------------- K4: per-bucket CSR build, 4B packed edges, pad-to-4 segments ----------------
__global__ __launch_bounds__(256) void bucket_csr(
        const u32* __restrict__ bbase, const Edge* __restrict__ etmp,
        u32* __restrict__ edges, int* __restrict__ offs, int* __restrict__ eoff,
        float* __restrict__ dinv) {
    int b = blockIdx.x;
    int t = threadIdx.x;
    u32 s = bbase[b], e = bbase[b + 1];
    int cnt = (int)(e - s);
    u32 rb = s + (u32)b * 1024u;         // padded region base (each bucket +1024 slack)
    int node0 = b << 8;
    int nloc = NN - node0; if (nloc > 256) nloc = 256;
    __shared__ u32 ncnt[256];
    __shared__ float nsum[256];
    __shared__ u32 ncur[256];
    __shared__ u32 sc[256];
    __shared__ u32 stage[CAP];   // 24 KB
    ncnt[t] = 0; nsum[t] = 0.f;
    __syncthreads();
    for (int i = t; i < cnt; i += 256) {
        Edge ed = etmp[s + i];
        u32 cl = ed.r >> 20;
        atomicAdd(&ncnt[cl], 1u);
        atomicAdd(&nsum[cl], ed.w);
    }
    __syncthreads();
    u32 v = ncnt[t];
    u32 pv = (v + 3u) & ~3u;             // pad each node's segment to multiple of 4
    sc[t] = pv;
    __syncthreads();
    for (int off = 1; off < 256; off <<= 1) {
        u32 u = (t >= off) ? sc[t - off] : 0;
        __syncthreads();
        sc[t] += u;
        __syncthreads();
    }
    u32 excl = sc[t] - pv;
    u32 ptot = sc[255];
    ncur[t] = excl;
    if (t < nloc) {
        offs[node0 + t] = (int)(rb + excl);
        eoff[node0 + t] = (int)(rb + excl + pv);
        float d = nsum[t];
        dinv[node0 + t] = d > 0.f ? rsqrtf(d) : 0.f;
    }
    __syncthreads();
    for (int i = t; i < cnt; i += 256) {
        Edge ed = etmp[s + i];
        u32 cl = ed.r >> 20;
        u32 slot = atomicAdd(&ncur[cl], 1u);
        u32 pw = (ed.r & ROWMASK) | (f2h_bits(ed.w) << 16);   // row fits 16 bits (NN<65536)
        if (slot < CAP) stage[slot] = pw;
        else edges[rb + slot] = pw;
    }
    if (t < nloc) {                      // zero-edge pads
        for (u32 slot = excl + v; slot < excl + pv; ++slot) {
            if (slot < CAP) stage[slot] = 0u;
            else edges[rb + slot] = 0u;
        }
    }
    __syncthreads();
    int lim = (int)(ptot < CAP ? ptot : CAP);
    for (int i = t; i < lim; i += 256) edges[rb + i] = stage[i];
}

// ---------------- pad/convert x to f16 stride 8; weight transposes; ghist clear ----------------
__global__ void pad_x(const float* __restrict__ x, f16* __restrict__ xpad,
                      const float* __restrict__ W1, const float* __restrict__ W2,
                      float* __restrict__ W1T, float* __restrict__ W2T,
                      u32* __restrict__ ghist) {
    int t = blockIdx.x * blockDim.x + threadIdx.x;
    if (t < NBKT) ghist[t] = 0;
    if (t < 30 * FH) {
        int f = t / 30, i = t - f * 30;
        W1T[t] = W1[i * FH + f];
        int k = i / 6, a = i - k * 6;
        W2T[t] = W2[((size_t)k * FH + f) * FO + a];
    }
    if (t >= NN8) return;
    int n = t >> 3, c = t & 7;
    xpad[t] = (c < 6) ? (f16)x[n * 6 + c] : (f16)0.f;
}

// ---------------- gather: one dwordx4 = 8 f16, use 6 ----------------
__device__ __forceinline__ void gath(const f16* __restrict__ xp, u32 r, float w,
                                     float& a0, float& a1, float& a2,
                                     float& a3, float& a4, float& a5) {
    f16x8 v = *(const f16x8*)(xp + (size_t)r * 8);
    a0 += w * (float)v[0]; a1 += w * (float)v[1]; a2 += w * (float)v[2];
    a3 += w * (float)v[3]; a4 += w * (float)v[4]; a5 += w * (float)v[5];
}

#define HOP_HEAD \
    int t = blockIdx.x * blockDim.x + threadIdx.x; \
    int n = t >> 2, j = t & 3; \
    if (n >= NN) return; \
    int s = offs[n], e = eoff[n]; \
    float a0 = 0.f, a1 = 0.f, a2 = 0.f, a3 = 0.f, a4 = 0.f, a5 = 0.f;

#define HOP_REDUCE \
    _Pragma("unroll") \
    for (int d = 1; d < 4; d <<= 1) { \
        a0 += __shfl_xor(a0, d); a1 += __shfl_xor(a1, d); a2 += __shfl_xor(a2, d); \
        a3 += __shfl_xor(a3, d); a4 += __shfl_xor(a4, d); a5 += __shfl_xor(a5, d); \
    }

// ---------------- hop: 4 lanes/node, 4 edges per int4; xnext(f16,8) = yadd + A*xprev ----------------
__global__ void hop4(const int* __restrict__ offs, const int* __restrict__ eoff,
                     const u32* __restrict__ edges,
                     const f16* __restrict__ xprev, const float* __restrict__ yadd,
                     f16* __restrict__ xnext) {
    HOP_HEAD
    for (int i = s + 4 * j; i < e; i += 16) {
        int4 q = *(const int4*)(edges + i);
        { u32 wd = (u32)q.x; gath(xprev, wd & 0xFFFFu, h2f_bits(wd >> 16), a0, a1, a2, a3, a4, a5); }
        { u32 wd = (u32)q.y; gath(xprev, wd & 0xFFFFu, h2f_bits(wd >> 16), a0, a1, a2, a3, a4, a5); }
        { u32 wd = (u32)q.z; gath(xprev, wd & 0xFFFFu, h2f_bits(wd >> 16), a0, a1, a2, a3, a4, a5); }
        { u32 wd = (u32)q.w; gath(xprev, wd & 0xFFFFu, h2f_bits(wd >> 16), a0, a1, a2, a3, a4, a5); }
    }
    HOP_REDUCE
    float v0 = j == 0 ? a0 : j == 1 ? a2 : j == 2 ? a4 : 0.f;
    float v1 = j == 0 ? a1 : j == 1 ? a3 : j == 2 ? a5 : 0.f;
    if (yadd && j < 3) {
        v0 += yadd[(size_t)n * 32 + 2 * j];
        v1 += yadd[(size_t)n * 32 + 2 * j + 1];
    }
    ((u32*)xnext)[(size_t)n * 4 + j] = pack2(v0, v1);
}

// ---------------- hop variant: normalize-in-place + first hop (gathers xpad) ----------------
__global__ void hop4_norm(const int* __restrict__ offs, const int* __restrict__ eoff,
                          u32* __restrict__ edges,
                          const float* __restrict__ dinv, const f16* __restrict__ xpad,
                          f16* __restrict__ xnext) {
    HOP_HEAD
    float dn = dinv[n];
    for (int i = s + 4 * j; i < e; i += 16) {
        int4 q = *(const int4*)(edges + i);
        int4 nq;
        { u32 wd = (u32)q.x; u32 r = wd & 0xFFFFu; float wn = h2f_bits(wd >> 16) * dn * dinv[r];
          nq.x = (int)(r | (f2h_bits(wn) << 16)); gath(xpad, r, wn, a0, a1, a2, a3, a4, a5); }
        { u32 wd = (u32)q.y; u32 r = wd & 0xFFFFu; float wn = h2f_bits(wd >> 16) * dn * dinv[r];
          nq.y = (int)(r | (f2h_bits(wn) << 16)); gath(xpad, r, wn, a0, a1, a2, a3, a4, a5); }
        { u32 wd = (u32)q.z; u32 r = wd & 0xFFFFu; float wn = h2f_bits(wd >> 16) * dn * dinv[r];
          nq.z = (int)(r | (f2h_bits(wn) << 16)); gath(xpad, r, wn, a0, a1, a2, a3, a4, a5); }
        { u32 wd = (u32)q.w; u32 r = wd & 0xFFFFu; float wn = h2f_bits(wd >> 16) * dn * dinv[r];
          nq.w = (int)(r | (f2h_bits(wn) << 16)); gath(xpad, r, wn, a0, a1, a2, a3, a4, a5); }
        *(int4*)(edges + i) = nq;        // persist normalized weights
    }
    HOP_REDUCE
    float v0 = j == 0 ? a0 : j == 1 ? a2 : j == 2 ? a4 : 0.f;
    float v1 = j == 0 ? a1 : j == 1 ? a3 : j == 2 ? a5 : 0.f;
    ((u32*)xnext)[(size_t)n * 4 + j] = pack2(v0, v1);
}

// ---------------- final hop fused with tanh/exp finalize ----------------
__global__ void hop4_final(const int* __restrict__ offs, const int* __restrict__ eoff,
                           const u32* __restrict__ edges,
                           const f16* __restrict__ xprev, const float* __restrict__ y0,
                           float* __restrict__ out) {
    HOP_HEAD
    for (int i = s + 4 * j; i < e; i += 16) {
        int4 q = *(const int4*)(edges + i);
        { u32 wd = (u32)q.x; gath(xprev, wd & 0xFFFFu, h2f_bits(wd >> 16), a0, a1, a2, a3, a4, a5); }
        { u32 wd = (u32)q.y; gath(xprev, wd & 0xFFFFu, h2f_bits(wd >> 16), a0, a1, a2, a3, a4, a5); }
        { u32 wd = (u32)q.z; gath(xprev, wd & 0xFFFFu, h2f_bits(wd >> 16), a0, a1, a2, a3, a4, a5); }
        { u32 wd = (u32)q.w; gath(xprev, wd & 0xFFFFu, h2f_bits(wd >> 16), a0, a1, a2, a3, a4, a5); }
    }
    HOP_REDUCE
    if (j < 3) {
        float mv = (j == 0 ? a0 : j == 1 ? a1 : a2) + y0[(size_t)n * 32 + j];
        float sv = (j == 0 ? a3 : j == 1 ? a4 : a5) + y0[(size_t)n * 32 + 3 + j];
        out[n * ADIM + j] = tanhf(mv);
        out[NN * ADIM + n * ADIM + j] = expf(2.f * tanhf(sv));
    }
}

// ---------------- fused dense v4: f-chunked for occupancy; partials to pacc ----------------
__global__ __launch_bounds__(256) void fused_dense_kernel(
        const float* __restrict__ x, const f16* __restrict__ xs,
        const float* __restrict__ W1T, const float* __restrict__ b1,
        const float* __restrict__ W2T,
        float* __restrict__ pacc) {
    int bb = blockIdx.x;
    int c = bb & (NCH - 1);
    int n = (bb >> 2) * 256 + threadIdx.x;
    if (n >= NN) return;
    float in[30];
    {
        const float* xr = x + (size_t)n * 6;
        float2 v0 = *(const float2*)xr;
        float2 v1 = *(const float2*)(xr + 2);
        float2 v2 = *(const float2*)(xr + 4);
        in[0] = v0.x; in[1] = v0.y; in[2] = v1.x;
        in[3] = v1.y; in[4] = v2.x; in[5] = v2.y;
    }
#pragma unroll
    for (int k = 0; k < 4; ++k) {
        f16x8 v = *(const f16x8*)(xs + (size_t)k * NN8 + (size_t)n * 8);
#pragma unroll
        for (int cc = 0; cc < 6; ++cc) in[6 + k * 6 + cc] = (float)v[cc];
    }
    float acc[32];
#pragma unroll
    for (int o = 0; o < 32; ++o) acc[o] = 0.f;
    int f0 = c * (FH / NCH);
#pragma unroll 2
    for (int fi = 0; fi < FH / NCH; ++fi) {
        int f = f0 + fi;
        const float* w1c = W1T + f * 30;   // wave-uniform -> scalar loads
        float h = b1[f];
#pragma unroll
        for (int i = 0; i < 30; ++i) h = fmaf(in[i], w1c[i], h);
        h = h > 0.f ? h : 0.f;
        const float* w2c = W2T + f * 30;
#pragma unroll
        for (int o = 0; o < 30; ++o) acc[o] = fmaf(h, w2c[o], acc[o]);
    }
    float* pr = pacc + ((size_t)c * NN + n) * 32;
#pragma unroll
    for (int o4 = 0; o4 < 8; ++o4)
        *(float4*)(pr + o4 * 4) = make_float4(acc[o4 * 4], acc[o4 * 4 + 1],
                                              acc[o4 * 4 + 2], acc[o4 * 4 + 3]);
}

// ---------------- reduce partials -> ys (fp32) + y4h (f16) ----------------
__global__ void reduce_dense(const float* __restrict__ pacc, const float* __restrict__ b2,
                             float* __restrict__ ys, f16* __restrict__ y4h) {
    int n = blockIdx.x * 256 + threadIdx.x;
    if (n >= NN) return;
    float acc[32];
#pragma unroll
    for (int o = 0; o < 32; ++o) acc[o] = 0.f;
#pragma unroll
    for (int c = 0; c < NCH; ++c) {
        const float* pr = pacc + ((size_t)c * NN + n) * 32;
#pragma unroll
        for (int o4 = 0; o4 < 8; ++o4) {
            float4 v = *(const float4*)(pr + o4 * 4);
            acc[o4 * 4 + 0] += v.x; acc[o4 * 4 + 1] += v.y;
            acc[o4 * 4 + 2] += v.z; acc[o4 * 4 + 3] += v.w;
        }
    }
#pragma unroll
    for (int o = 0; o < 6; ++o) acc[o] += b2[o];
    float* yr = ys + (size_t)n * 32;
#pragma unroll
    for (int o4 = 0; o4 < 6; ++o4)
        *(float4*)(yr + o4 * 4) = make_float4(acc[o4 * 4], acc[o4 * 4 + 1],
                                              acc[o4 * 4 + 2], acc[o4 * 4 + 3]);
    u32* yh = (u32*)(y4h + (size_t)n * 8);
    yh[0] = pack2(acc[24], acc[25]);
    yh[1] = pack2(acc[26], acc[27]);
    yh[2] = pack2(acc[28], acc[29]);
}

extern "C" void kernel_launch(void* const* d_in, const int* in_sizes, int n_in,
                              void* d_out, int out_size, void* d_ws, size_t ws_size,
                              hipStream_t stream) {
    const float* x  = (const float*)d_in[0];
    const int*   ei = (const int*)d_in[1];
    const float* ew = (const float*)d_in[2];
    const float* W1 = (const float*)d_in[3];
    const float* b1 = (const float*)d_in[4];
    const float* W2 = (const float*)d_in[5];
    const float* b2 = (const float*)d_in[6];
    float* out = (float*)d_out;

    const int* row = ei;
    const int* col = ei + NE;

    // workspace layout: f16 planes first (16B-aligned, sizes multiple of 16B)
    f16*   xpad  = (f16*)d_ws;                  // NN8
    f16*   xs    = xpad + NN8;                  // KH*NN8
    f16*   y4h   = xs + (size_t)KH * NN8;       // NN8
    f16*   za    = y4h + NN8;                   // NN8
    f16*   zb    = za + NN8;                    // NN8
    float* ys    = (float*)(zb + NN8);          // NN*32 fp32
    float* pacc  = ys + (size_t)NN * 32;        // NCH*NN*32 fp32
    float* W1T   = pacc + (size_t)NCH * NN * 32; // 3840
    float* W2T   = W1T + 30 * FH;               // 3840
    Edge*  etmp  = (Edge*)(W2T + 30 * FH);      // NE (8B)
    u32*   edges = (u32*)(etmp + NE);           // NEPAD (4B packed)
    u32*   ghist = edges + NEPAD;               // NBKT
    u32*   bbase = ghist + NBKT;                // NBKT+1
    u32*   bcur  = bbase + NBKT + 1;            // NBKT
    int*   offs  = (int*)(bcur + NBKT);         // NN
    int*   eoff  = offs + NN;                   // NN
    float* dinv  = (float*)(eoff + NN);         // NN

    const int B = 256;
    const int gHop = (NN * 4 + B - 1) / B;
    const int gPad = (NN8 + B - 1) / B;

    // ---- CSR build (ghist clear + weight transpose folded into pad_x) ----
    pad_x<<<gPad, B, 0, stream>>>(x, xpad, W1, W2, W1T, W2T, ghist);
    bucket_hist<<<NPB, B, 0, stream>>>(col, ghist);
    bucket_scan<<<1, B, 0, stream>>>(ghist, bbase, bcur);
    partition_kernel<<<NPB, B, 0, stream>>>(row, col, ew, bcur, etmp);
    bucket_csr<<<NBKT, B, 0, stream>>>(bbase, etmp, edges, offs, eoff, dinv);

    // ---- layer 1: hops (hop 1 fuses normalization) ----
    hop4_norm<<<gHop, B, 0, stream>>>(offs, eoff, edges, dinv, xpad, xs);
    for (int k = 2; k <= KH; ++k)
        hop4<<<gHop, B, 0, stream>>>(offs, eoff, edges,
                                     xs + (size_t)(k - 2) * NN8, nullptr,
                                     xs + (size_t)(k - 1) * NN8);

    // ---- fused dense1 + relu + proj2 (f-chunked) + reduce ----
    fused_dense_kernel<<<NDB * NCH, B, 0, stream>>>(x, xs, W1T, b1, W2T, pacc);
    reduce_dense<<<NDB, B, 0, stream>>>(pacc, b2, ys, y4h);

    // ---- layer 2 Horner on 6-wide ----
    hop4<<<gHop, B, 0, stream>>>(offs, eoff, edges, y4h, ys + 18, za);
    hop4<<<gHop, B, 0, stream>>>(offs, eoff, edges, za, ys + 12, zb);
    hop4<<<gHop, B, 0, stream>>>(offs, eoff, edges, zb, ys + 6, za);
    hop4_final<<<gHop, B, 0, stream>>>(offs, eoff, edges, za, ys, out);
}